// Round 8
// baseline (178.357 us; speedup 1.0000x reference)
//
#include <hip/hip_runtime.h>
#include <math.h>

// QGRUCell — Round 8: single fused GEMM kernel. A-fragments (x, h) are loaded
// DIRECTLY from global row-major fp32 (frag layout is row-contiguous in K) and
// converted to f16 in-register — no transpose pre-pass, no A workspace.
// Weights only: tiny 96-block cvt pre-tiles [wih;whh] into frag-order f16
// chunks in d_ws; main stages them with contiguous 1KB global_load_lds DMA,
// double-buffered (KT=32, 48KB LDS, 3 blocks/CU).

typedef _Float16 f16x8  __attribute__((ext_vector_type(8)));
typedef _Float16 f16x4  __attribute__((ext_vector_type(4)));
typedef __bf16   bf16x8 __attribute__((ext_vector_type(8)));
typedef float    f32x16 __attribute__((ext_vector_type(16)));

namespace {

constexpr int Bsz = 8192, Ksz = 512, Hsz = 512;
constexpr int BM = 64, BN = 64;

// ws (f16): W only. chunk(g, N32, K16) = (g*16+N32)*32 + K16, 512 f16 each,
// chunk pos(row,k) = (k>>3)*256 + row*8 + (k&7). 3072 chunks = 3 MB.
constexpr unsigned NCHW    = 3072u;
constexpr size_t   WS_NEED = (size_t)NCHW * 512u * 2u;   // 3,145,728 B

__device__ __forceinline__ float qround(float x, float s, float invs) {
    return floorf(x * s + 0.5f) * invs;
}

__device__ __forceinline__ float qsigmoid_dev(float x) {
    float iq = floorf(x * 134217728.0f + 0.5f);
    iq = fminf(fmaxf(iq, -2147483648.0f), 2147483648.0f);
    float e = __expf(-iq * 7.450580596923828125e-9f);
    float s = __builtin_amdgcn_rcpf(1.0f + e);
    float q31 = floorf(s * 2147483648.0f + 0.5f);
    float q15 = floorf(q31 * 1.52587890625e-5f + 0.5f);
    return q15 * 3.0517578125e-5f;
}

__device__ __forceinline__ float qtanh_dev(float x) {
    float iq = floorf(x * 134217728.0f + 0.5f);
    iq = fminf(fmaxf(iq, -2147483648.0f), 2147483648.0f);
    float z = iq * 7.450580596923828125e-9f;
    float e = __expf(2.0f * z);
    float t = 1.0f - 2.0f * __builtin_amdgcn_rcpf(e + 1.0f);
    float q31 = floorf(t * 2147483648.0f + 0.5f);
    float q15 = floorf(q31 * 1.52587890625e-5f + 0.5f);
    return q15 * 3.0517578125e-5f;
}

__device__ __forceinline__ void dma16(const void* g, void* l) {
    __builtin_amdgcn_global_load_lds(
        (const __attribute__((address_space(1))) unsigned int*)g,
        (__attribute__((address_space(3))) unsigned int*)l, 16, 0, 0);
}

__device__ __forceinline__ f16x8 cvt8(float4 a, float4 b) {   // RNE casts
    f16x8 r;
    r[0] = (_Float16)a.x; r[1] = (_Float16)a.y;
    r[2] = (_Float16)a.z; r[3] = (_Float16)a.w;
    r[4] = (_Float16)b.x; r[5] = (_Float16)b.y;
    r[6] = (_Float16)b.z; r[7] = (_Float16)b.w;
    return r;
}

__device__ __forceinline__ void split2(float a, float b, unsigned& hi, unsigned& lo) {
    unsigned ua = __float_as_uint(a); ua += 0x7fffu + ((ua >> 16) & 1u);
    unsigned ub = __float_as_uint(b); ub += 0x7fffu + ((ub >> 16) & 1u);
    hi = (ua >> 16) | (ub & 0xffff0000u);
    float ra = a - __uint_as_float(ua & 0xffff0000u);
    float rb = b - __uint_as_float(ub & 0xffff0000u);
    unsigned va = __float_as_uint(ra); va += 0x7fffu + ((va >> 16) & 1u);
    unsigned vb = __float_as_uint(rb); vb += 0x7fffu + ((vb >> 16) & 1u);
    lo = (va >> 16) | (vb & 0xffff0000u);
}

} // namespace

// ---------------- pre-pass: weights fp32 -> f16 frag-order chunks ----------
// 96 blocks; one block per (gate g, col-group N32): 32 rows x 512 k.
// LDS-tile transpose (R7-validated), both global sides coalesced.
__global__ __launch_bounds__(256) void wcvt_f16(
    const float* __restrict__ wih, const float* __restrict__ whh,
    _Float16* __restrict__ ws)
{
    __shared__ __align__(16) _Float16 lt[16384];

    const int b   = blockIdx.x;            // 0..95
    const int tid = threadIdx.x;
    const int g   = b >> 4, N32 = b & 15;
    const int rowLocal = (g % 3) * 512 + N32 * 32;
    const float* src = (g < 3 ? wih : whh) + (size_t)rowLocal * 512u;
    const unsigned chbase = (unsigned)((g * 16 + N32) * 32);

#pragma unroll
    for (int rep = 0; rep < 16; ++rep) {
        const int idx = rep * 256 + tid;
        const int row = idx >> 7;
        const int q   = idx & 127;
        const float4 v = *(const float4*)(src + (size_t)row * 512 + q * 4);
        const int K16  = q >> 2;
        const int kh   = (q >> 1) & 1;
        const int half = (q & 1) * 4;
        const int rsw  = (row + (q >> 1)) & 31;
        f16x4 o;
        o[0] = (_Float16)v.x; o[1] = (_Float16)v.y;
        o[2] = (_Float16)v.z; o[3] = (_Float16)v.w;
        *(f16x4*)&lt[K16 * 512 + kh * 256 + rsw * 8 + half] = o;
    }
    __syncthreads();

    const int wid = tid >> 6, lane = tid & 63;
    const int kh  = lane >> 5, row = lane & 31;
#pragma unroll
    for (int cc = 0; cc < 8; ++cc) {
        const int K16 = wid * 8 + cc;
        const int rsw = (row + 2 * K16 + kh) & 31;
        const f16x8 o = *(const f16x8*)&lt[K16 * 512 + kh * 256 + rsw * 8];
        *(f16x8*)(ws + (size_t)(chbase + K16) * 512u + lane * 8) = o;
    }
}

// ---------------- main: fused GEMM + quantized GRU epilogue ----------------
// Slab = 24 chunks x 512 f16 = 24KB: chunk (g,ntc,ks2) at ((g*2+ntc)*2+ks2)*512.
// A-frags: lane reads 32B (float4 x2) straight from x/h row-major, cvt to f16.
__global__ __launch_bounds__(256, 3) void qgru_fused_f16(
    const float* __restrict__ x, const float* __restrict__ hid,
    const _Float16* __restrict__ ws,
    const float* __restrict__ bih, const float* __restrict__ bhh,
    float* __restrict__ out)
{
    __shared__ __align__(16) _Float16 lds[24576];   // 48 KB (2 x 24KB slabs)

    const int t = threadIdx.x, lane = t & 63, wid = t >> 6;
    const int mt = wid >> 1, nt = wid & 1;
    const int m0 = blockIdx.x * BM, n0 = blockIdx.y * BN;

    // W DMA table: wave handles 6 of 24 chunks/step
    unsigned goff[6];
    int      ldst[6];
#pragma unroll
    for (int c = 0; c < 6; ++c) {
        const int q = wid * 6 + c;              // 0..23
        const int g = q >> 2, ntc = (q >> 1) & 1, ks2 = q & 1;
        const unsigned ch = (unsigned)((g * 16 + (n0 >> 5) + ntc) * 32) + (unsigned)ks2;
        goff[c] = ch * 1024u + (unsigned)lane * 16u;
        ldst[c] = ((g * 2 + ntc) * 2 + ks2) * 512;
    }

    // A-frag global row pointers (frag is row-contiguous in k)
    const int arow = m0 + mt * 32 + (lane & 31);
    const int koff = (lane >> 5) * 8;
    const float* pax = x   + (size_t)arow * Ksz + koff;
    const float* pah = hid + (size_t)arow * Ksz + koff;

    f32x16 acc[6];
#pragma unroll
    for (int g = 0; g < 6; ++g)
#pragma unroll
        for (int i = 0; i < 16; ++i) acc[g][i] = 0.0f;

    const char* wsb = (const char*)ws;
    const int lfo = (lane >> 5) * 256 + (lane & 31) * 8;

    // pre-issue step 0 W into slab 0
#pragma unroll
    for (int c = 0; c < 6; ++c)
        dma16(wsb + goff[c], &lds[ldst[c]]);

    for (int step = 0; step < 16; ++step) {
        __syncthreads();   // current slab's DMA drained; prev slab reads done

        if (step + 1 < 16) {
            const unsigned kb = (unsigned)(step + 1) * 2048u;
            const int nb = ((step + 1) & 1) * 12288;
#pragma unroll
            for (int c = 0; c < 6; ++c)
                dma16(wsb + goff[c] + kb, &lds[nb + ldst[c]]);
        }

        const int cb = (step & 1) * 12288;
        const int kbase = step * 32;
#pragma unroll
        for (int ks2 = 0; ks2 < 2; ++ks2) {
            const int ke = kbase + ks2 * 16;
            const float4 a0 = *(const float4*)(pax + ke);
            const float4 a1 = *(const float4*)(pax + ke + 4);
            const float4 h0 = *(const float4*)(pah + ke);
            const float4 h1 = *(const float4*)(pah + ke + 4);
            const f16x8 ax = cvt8(a0, a1);
            const f16x8 ah = cvt8(h0, h1);
#pragma unroll
            for (int g = 0; g < 6; ++g) {
                const f16x8 b = *(const f16x8*)&lds[cb + ((g * 2 + nt) * 2 + ks2) * 512 + lfo];
                acc[g] = __builtin_amdgcn_mfma_f32_32x32x16_f16(
                             g < 3 ? ax : ah, b, acc[g], 0, 0, 0);
            }
        }
    }

    // ---- epilogue: quantized GRU gate chain ----
    constexpr float S14 = 16384.0f,     I14 = 1.0f / 16384.0f;
    constexpr float S15 = 32768.0f,     I15 = 1.0f / 32768.0f;
    constexpr float S27 = 134217728.0f, I27 = 1.0f / 134217728.0f;

    const int lh = lane >> 5, l32 = lane & 31;
    const int n = n0 + nt * 32 + l32;
    const float br = bih[n], bi = bih[n + 512], bn = bih[n + 1024];
    const float cr = bhh[n], ci = bhh[n + 512], cn = bhh[n + 1024];

#pragma unroll
    for (int r = 0; r < 16; ++r) {
        const int row = (r & 3) + 8 * (r >> 2) + 4 * lh;
        const int m   = m0 + mt * 32 + row;
        const float hv = hid[(size_t)m * Hsz + n];

        float gir = qround(acc[0][r] + br, S14, I14);
        float gii = qround(acc[1][r] + bi, S14, I14);
        float gin = qround(acc[2][r] + bn, S14, I14);
        float ghr = qround(acc[3][r] + cr, S14, I14);
        float ghi = qround(acc[4][r] + ci, S14, I14);
        float ghn = qround(acc[5][r] + cn, S14, I14);
        float resetg = qsigmoid_dev(gir + ghr);
        float inputg = qsigmoid_dev(gii + ghi);
        float hn  = qround(ghn, S27, I27);
        float rh  = qround(resetg * hn, S15, I15);
        float newg = qtanh_dev(rh + gin);
        float nh  = qround(hv, S15, I15);
        out[(size_t)m * Hsz + n] = newg + inputg * (nh - newg);
    }
}

// ---------------- fallback: bf16x3 (used only if ws too small) -------------
__global__ __launch_bounds__(256, 2) void qgru_mfma_bf16x3(
    const float* __restrict__ x, const float* __restrict__ hid,
    const float* __restrict__ wih, const float* __restrict__ whh,
    const float* __restrict__ bih, const float* __restrict__ bhh,
    float* __restrict__ out)
{
    __shared__ __align__(16) unsigned short lds[16384];

    const int t = threadIdx.x, lane = t & 63, wid = t >> 6;
    const int mt = wid >> 1, nt = wid & 1;
    const int m0 = blockIdx.x * BM, n0 = blockIdx.y * BN;
    const int s_r = t >> 2, s_k = (t & 3) << 2;
    const int s_kh = s_k >> 3, s_j = s_k & 7, s_rt = s_r >> 5, s_r32 = s_r & 31;

    const float* gA[2];
    gA[0] = x   + (size_t)(m0 + s_r) * Ksz + s_k;
    gA[1] = hid + (size_t)(m0 + s_r) * Ksz + s_k;
    const float* gW[6];
#pragma unroll
    for (int g = 0; g < 3; ++g) {
        gW[g]     = wih + (size_t)(g * Hsz + n0 + s_r) * Ksz + s_k;
        gW[g + 3] = whh + (size_t)(g * Hsz + n0 + s_r) * Ksz + s_k;
    }
    const int lh = lane >> 5, l32 = lane & 31;

    f32x16 acc[6];
#pragma unroll
    for (int g = 0; g < 6; ++g)
#pragma unroll
        for (int i = 0; i < 16; ++i) acc[g][i] = 0.0f;

    float4 vA[2], vW[6];
#pragma unroll
    for (int tt = 0; tt < 2; ++tt) vA[tt] = *(const float4*)gA[tt];
#pragma unroll
    for (int g = 0; g < 6; ++g)    vW[g]  = *(const float4*)gW[g];

    for (int k0 = 0; k0 < Ksz; k0 += 16) {
        __syncthreads();
#pragma unroll
        for (int tt = 0; tt < 2; ++tt) {
            unsigned h0, h1, l0, l1;
            split2(vA[tt].x, vA[tt].y, h0, l0);
            split2(vA[tt].z, vA[tt].w, h1, l1);
            unsigned bH = ((((tt*2+0)*2+s_rt)*2+s_kh)*32+s_r32)*8 + s_j;
            unsigned bL = ((((tt*2+1)*2+s_rt)*2+s_kh)*32+s_r32)*8 + s_j;
            *reinterpret_cast<uint2*>(&lds[bH]) = make_uint2(h0, h1);
            *reinterpret_cast<uint2*>(&lds[bL]) = make_uint2(l0, l1);
        }
#pragma unroll
        for (int g = 0; g < 6; ++g) {
            unsigned h0, h1, l0, l1;
            split2(vW[g].x, vW[g].y, h0, l0);
            split2(vW[g].z, vW[g].w, h1, l1);
            unsigned bH = 4096u + ((((g*2+0)*2+s_rt)*2+s_kh)*32+s_r32)*8 + s_j;
            unsigned bL = 4096u + ((((g*2+1)*2+s_rt)*2+s_kh)*32+s_r32)*8 + s_j;
            *reinterpret_cast<uint2*>(&lds[bH]) = make_uint2(h0, h1);
            *reinterpret_cast<uint2*>(&lds[bL]) = make_uint2(l0, l1);
        }
        __syncthreads();
        const int kn = (k0 + 16 < Ksz) ? (k0 + 16) : 0;
#pragma unroll
        for (int tt = 0; tt < 2; ++tt) vA[tt] = *(const float4*)(gA[tt] + kn);
#pragma unroll
        for (int g = 0; g < 6; ++g)    vW[g]  = *(const float4*)(gW[g] + kn);

        const bf16x8 ax_hi = *reinterpret_cast<const bf16x8*>(&lds[((((0)*2+mt)*2+lh)*32+l32)*8]);
        const bf16x8 ax_lo = *reinterpret_cast<const bf16x8*>(&lds[((((1)*2+mt)*2+lh)*32+l32)*8]);
        const bf16x8 ah_hi = *reinterpret_cast<const bf16x8*>(&lds[((((2)*2+mt)*2+lh)*32+l32)*8]);
        const bf16x8 ah_lo = *reinterpret_cast<const bf16x8*>(&lds[((((3)*2+mt)*2+lh)*32+l32)*8]);
#pragma unroll
        for (int g = 0; g < 6; ++g) {
            const bf16x8 b_hi = *reinterpret_cast<const bf16x8*>(&lds[4096u + ((((g*2+0)*2+nt)*2+lh)*32+l32)*8]);
            const bf16x8 b_lo = *reinterpret_cast<const bf16x8*>(&lds[4096u + ((((g*2+1)*2+nt)*2+lh)*32+l32)*8]);
            const bf16x8 a_hi = (g < 3) ? ax_hi : ah_hi;
            const bf16x8 a_lo = (g < 3) ? ax_lo : ah_lo;
            acc[g] = __builtin_amdgcn_mfma_f32_32x32x16_bf16(a_hi, b_hi, acc[g], 0, 0, 0);
            acc[g] = __builtin_amdgcn_mfma_f32_32x32x16_bf16(a_hi, b_lo, acc[g], 0, 0, 0);
            acc[g] = __builtin_amdgcn_mfma_f32_32x32x16_bf16(a_lo, b_hi, acc[g], 0, 0, 0);
        }
    }

    constexpr float S14 = 16384.0f,     I14 = 1.0f / 16384.0f;
    constexpr float S15 = 32768.0f,     I15 = 1.0f / 32768.0f;
    constexpr float S27 = 134217728.0f, I27 = 1.0f / 134217728.0f;
    const int n = n0 + nt * 32 + l32;
    const float br = bih[n], bi = bih[n + 512], bn = bih[n + 1024];
    const float cr = bhh[n], ci = bhh[n + 512], cn = bhh[n + 1024];
#pragma unroll
    for (int r = 0; r < 16; ++r) {
        const int row = (r & 3) + 8 * (r >> 2) + 4 * lh;
        const int m   = m0 + mt * 32 + row;
        const float hv = hid[(size_t)m * Hsz + n];
        float gir = qround(acc[0][r] + br, S14, I14);
        float gii = qround(acc[1][r] + bi, S14, I14);
        float gin = qround(acc[2][r] + bn, S14, I14);
        float ghr = qround(acc[3][r] + cr, S14, I14);
        float ghi = qround(acc[4][r] + ci, S14, I14);
        float ghn = qround(acc[5][r] + cn, S14, I14);
        float resetg = qsigmoid_dev(gir + ghr);
        float inputg = qsigmoid_dev(gii + ghi);
        float hn  = qround(ghn, S27, I27);
        float rh  = qround(resetg * hn, S15, I15);
        float newg = qtanh_dev(rh + gin);
        float nh  = qround(hv, S15, I15);
        out[(size_t)m * Hsz + n] = newg + inputg * (nh - newg);
    }
}

extern "C" void kernel_launch(void* const* d_in, const int* in_sizes, int n_in,
                              void* d_out, int out_size, void* d_ws, size_t ws_size,
                              hipStream_t stream) {
    const float* x   = (const float*)d_in[0];
    const float* hid = (const float*)d_in[1];
    const float* wih = (const float*)d_in[2];
    const float* whh = (const float*)d_in[3];
    const float* bih = (const float*)d_in[4];
    const float* bhh = (const float*)d_in[5];
    float* out = (float*)d_out;
    dim3 grid(Bsz / BM, Hsz / BN);   // x-major: consecutive blocks share W chunks

    if (ws_size >= WS_NEED) {
        wcvt_f16<<<96, 256, 0, stream>>>(wih, whh, (_Float16*)d_ws);
        qgru_fused_f16<<<grid, dim3(256), 0, stream>>>(
            x, hid, (const _Float16*)d_ws, bih, bhh, out);
    } else {
        qgru_mfma_bf16x3<<<grid, dim3(256), 0, stream>>>(
            x, hid, wih, whh, bih, bhh, out);
    }
}

// Round 9
// 139.731 us; speedup vs baseline: 1.2764x; 1.2764x over previous
//
#include <hip/hip_runtime.h>
#include <math.h>

// QGRUCell — Round 9: hybrid staging.
//   W: pre-tiled f16 chunks in d_ws (96-block wcvt) + contiguous 1KB
//      global_load_lds DMA (validated R5/R8 path).
//   A (x,h): block-cooperative coalesced float4 reads (4 lanes = 1 full
//      128B line) -> in-register f16 cvt -> ds_write_b128 into frag-order
//      LDS chunks. No A workspace, no A transpose kernel.
// KT=32, 32KB slab (A 8KB + W 24KB), double-buffered 64KB, 16 barriers.
// Rule learned R4/R5/R8: every global access must be segment-contiguous per
// wave — scattered 16B/lane costs ~10x its bytes in TA requests.

typedef _Float16 f16x8  __attribute__((ext_vector_type(8)));
typedef _Float16 f16x4  __attribute__((ext_vector_type(4)));
typedef __bf16   bf16x8 __attribute__((ext_vector_type(8)));
typedef float    f32x16 __attribute__((ext_vector_type(16)));

namespace {

constexpr int Bsz = 8192, Ksz = 512, Hsz = 512;
constexpr int BM = 64, BN = 64;

// ws (f16): W only. chunk(g, N32, K16) = (g*16+N32)*32 + K16, 512 f16 each,
// chunk pos(row,k) = (k>>3)*256 + row*8 + (k&7). 3072 chunks = 3 MB.
constexpr unsigned NCHW    = 3072u;
constexpr size_t   WS_NEED = (size_t)NCHW * 512u * 2u;   // 3,145,728 B

__device__ __forceinline__ float qround(float x, float s, float invs) {
    return floorf(x * s + 0.5f) * invs;
}

__device__ __forceinline__ float qsigmoid_dev(float x) {
    float iq = floorf(x * 134217728.0f + 0.5f);
    iq = fminf(fmaxf(iq, -2147483648.0f), 2147483648.0f);
    float e = __expf(-iq * 7.450580596923828125e-9f);
    float s = __builtin_amdgcn_rcpf(1.0f + e);
    float q31 = floorf(s * 2147483648.0f + 0.5f);
    float q15 = floorf(q31 * 1.52587890625e-5f + 0.5f);
    return q15 * 3.0517578125e-5f;
}

__device__ __forceinline__ float qtanh_dev(float x) {
    float iq = floorf(x * 134217728.0f + 0.5f);
    iq = fminf(fmaxf(iq, -2147483648.0f), 2147483648.0f);
    float z = iq * 7.450580596923828125e-9f;
    float e = __expf(2.0f * z);
    float t = 1.0f - 2.0f * __builtin_amdgcn_rcpf(e + 1.0f);
    float q31 = floorf(t * 2147483648.0f + 0.5f);
    float q15 = floorf(q31 * 1.52587890625e-5f + 0.5f);
    return q15 * 3.0517578125e-5f;
}

__device__ __forceinline__ void dma16(const void* g, void* l) {
    __builtin_amdgcn_global_load_lds(
        (const __attribute__((address_space(1))) unsigned int*)g,
        (__attribute__((address_space(3))) unsigned int*)l, 16, 0, 0);
}

__device__ __forceinline__ f16x8 cvt8(float4 a, float4 b) {   // RNE casts
    f16x8 r;
    r[0] = (_Float16)a.x; r[1] = (_Float16)a.y;
    r[2] = (_Float16)a.z; r[3] = (_Float16)a.w;
    r[4] = (_Float16)b.x; r[5] = (_Float16)b.y;
    r[6] = (_Float16)b.z; r[7] = (_Float16)b.w;
    return r;
}

__device__ __forceinline__ void split2(float a, float b, unsigned& hi, unsigned& lo) {
    unsigned ua = __float_as_uint(a); ua += 0x7fffu + ((ua >> 16) & 1u);
    unsigned ub = __float_as_uint(b); ub += 0x7fffu + ((ub >> 16) & 1u);
    hi = (ua >> 16) | (ub & 0xffff0000u);
    float ra = a - __uint_as_float(ua & 0xffff0000u);
    float rb = b - __uint_as_float(ub & 0xffff0000u);
    unsigned va = __float_as_uint(ra); va += 0x7fffu + ((va >> 16) & 1u);
    unsigned vb = __float_as_uint(rb); vb += 0x7fffu + ((vb >> 16) & 1u);
    lo = (va >> 16) | (vb & 0xffff0000u);
}

} // namespace

// ---------------- pre-pass: weights fp32 -> f16 frag-order chunks ----------
// 96 blocks, one per (gate g, N32 col-group). LDS-tile transpose, both
// global sides coalesced. Validated in R8.
__global__ __launch_bounds__(256) void wcvt_f16(
    const float* __restrict__ wih, const float* __restrict__ whh,
    _Float16* __restrict__ ws)
{
    __shared__ __align__(16) _Float16 lt[16384];

    const int b   = blockIdx.x;            // 0..95
    const int tid = threadIdx.x;
    const int g   = b >> 4, N32 = b & 15;
    const int rowLocal = (g % 3) * 512 + N32 * 32;
    const float* src = (g < 3 ? wih : whh) + (size_t)rowLocal * 512u;
    const unsigned chbase = (unsigned)((g * 16 + N32) * 32);

#pragma unroll
    for (int rep = 0; rep < 16; ++rep) {
        const int idx = rep * 256 + tid;
        const int row = idx >> 7;
        const int q   = idx & 127;
        const float4 v = *(const float4*)(src + (size_t)row * 512 + q * 4);
        const int K16  = q >> 2;
        const int kh   = (q >> 1) & 1;
        const int half = (q & 1) * 4;
        const int rsw  = (row + (q >> 1)) & 31;
        f16x4 o;
        o[0] = (_Float16)v.x; o[1] = (_Float16)v.y;
        o[2] = (_Float16)v.z; o[3] = (_Float16)v.w;
        *(f16x4*)&lt[K16 * 512 + kh * 256 + rsw * 8 + half] = o;
    }
    __syncthreads();

    const int wid = tid >> 6, lane = tid & 63;
    const int kh  = lane >> 5, row = lane & 31;
#pragma unroll
    for (int cc = 0; cc < 8; ++cc) {
        const int K16 = wid * 8 + cc;
        const int rsw = (row + 2 * K16 + kh) & 31;
        const f16x8 o = *(const f16x8*)&lt[K16 * 512 + kh * 256 + rsw * 8];
        *(f16x8*)(ws + (size_t)(chbase + K16) * 512u + lane * 8) = o;
    }
}

// ---------------- main: hybrid-staged GEMM + quantized GRU epilogue --------
// Slab (16384 f16 = 32KB): A chunk ((arr*2+mtc)*2+ks2)*512   [0,4096)
//                          W chunk 4096 + ((g*2+ntc)*2+ks2)*512
__global__ __launch_bounds__(256, 2) void qgru_hyb(
    const float* __restrict__ x, const float* __restrict__ hid,
    const _Float16* __restrict__ ws,
    const float* __restrict__ bih, const float* __restrict__ bhh,
    float* __restrict__ out)
{
    __shared__ __align__(16) _Float16 lds[32768];   // 64 KB (2 x 32KB slabs)

    const int t = threadIdx.x, lane = t & 63, wid = t >> 6;
    const int mt = wid >> 1, nt = wid & 1;
    const int m0 = blockIdx.x * BM, n0 = blockIdx.y * BN;

    // ---- W DMA table: 24 chunks/step, 6 per wave, 1KB contiguous each ----
    unsigned goff[6];
    int      ldst[6];
#pragma unroll
    for (int c = 0; c < 6; ++c) {
        const int q = wid * 6 + c;              // 0..23
        const int g = q >> 2, ntc = (q >> 1) & 1, ks2 = q & 1;
        const unsigned ch = (unsigned)((g * 16 + (n0 >> 5) + ntc) * 32) + (unsigned)ks2;
        goff[c] = ch * 1024u + (unsigned)lane * 16u;
        ldst[c] = 4096 + ((g * 2 + ntc) * 2 + ks2) * 512;
    }

    // ---- A staging descriptors: 2 reps x 256 threads cover 2 arr x 64 rows
    //      x 4 k-octets. Lane group of 4 covers one full 128B line. ----
    const float* asrc_[2];
    int adst_[2];
#pragma unroll
    for (int r = 0; r < 2; ++r) {
        const int idx  = r * 256 + t;
        const int arr  = idx >> 8, row = (idx >> 2) & 63, koct = idx & 3;
        asrc_[r] = (arr ? hid : x) + (size_t)(m0 + row) * Ksz + koct * 8;
        adst_[r] = ((arr * 2 + (row >> 5)) * 2 + (koct >> 1)) * 512
                 + (koct & 1) * 256 + (row & 31) * 8;
    }

    f32x16 acc[6];
#pragma unroll
    for (int g = 0; g < 6; ++g)
#pragma unroll
        for (int i = 0; i < 16; ++i) acc[g][i] = 0.0f;

    const char* wsb = (const char*)ws;
    const int lfo = (lane >> 5) * 256 + (lane & 31) * 8;

    // ---- prologue: stage step 0 into slab 0 ----
#pragma unroll
    for (int c = 0; c < 6; ++c)
        dma16(wsb + goff[c], &lds[ldst[c]]);
#pragma unroll
    for (int r = 0; r < 2; ++r) {
        const float4 v0 = *(const float4*)asrc_[r];
        const float4 v1 = *(const float4*)(asrc_[r] + 4);
        *(f16x8*)&lds[adst_[r]] = cvt8(v0, v1);
    }

    for (int step = 0; step < 16; ++step) {
        __syncthreads();   // slab's DMA + ds_writes drained; prev reads done

        // prefetch step+1: W-DMA + A global loads (issue early for latency)
        float4 p0[2], p1[2];
        const bool pf = (step + 1 < 16);
        if (pf) {
            const unsigned kb = (unsigned)(step + 1) * 2048u;
            const int nb = ((step + 1) & 1) * 16384;
#pragma unroll
            for (int c = 0; c < 6; ++c)
                dma16(wsb + goff[c] + kb, &lds[nb + ldst[c]]);
#pragma unroll
            for (int r = 0; r < 2; ++r) {
                p0[r] = *(const float4*)(asrc_[r] + (step + 1) * 32);
                p1[r] = *(const float4*)(asrc_[r] + (step + 1) * 32 + 4);
            }
        }

        // compute current slab
        const int cb = (step & 1) * 16384;
#pragma unroll
        for (int ks2 = 0; ks2 < 2; ++ks2) {
            const int lf = cb + ks2 * 512 + lfo;
            const f16x8 ax = *(const f16x8*)&lds[lf + mt * 1024];
            const f16x8 ah = *(const f16x8*)&lds[lf + (2 + mt) * 1024];
#pragma unroll
            for (int g = 0; g < 6; ++g) {
                const f16x8 b = *(const f16x8*)&lds[lf + 4096 + (g * 2 + nt) * 1024];
                acc[g] = __builtin_amdgcn_mfma_f32_32x32x16_f16(
                             g < 3 ? ax : ah, b, acc[g], 0, 0, 0);
            }
        }

        // A ds_writes after compute (keeps in-order lgkm queue off frag reads)
        if (pf) {
            const int nb = ((step + 1) & 1) * 16384;
#pragma unroll
            for (int r = 0; r < 2; ++r)
                *(f16x8*)&lds[nb + adst_[r]] = cvt8(p0[r], p1[r]);
        }
    }

    // ---- epilogue: quantized GRU gate chain ----
    constexpr float S14 = 16384.0f,     I14 = 1.0f / 16384.0f;
    constexpr float S15 = 32768.0f,     I15 = 1.0f / 32768.0f;
    constexpr float S27 = 134217728.0f, I27 = 1.0f / 134217728.0f;

    const int lh = lane >> 5, l32 = lane & 31;
    const int n = n0 + nt * 32 + l32;
    const float br = bih[n], bi = bih[n + 512], bn = bih[n + 1024];
    const float cr = bhh[n], ci = bhh[n + 512], cn = bhh[n + 1024];

#pragma unroll
    for (int r = 0; r < 16; ++r) {
        const int row = (r & 3) + 8 * (r >> 2) + 4 * lh;
        const int m   = m0 + mt * 32 + row;
        const float hv = hid[(size_t)m * Hsz + n];

        float gir = qround(acc[0][r] + br, S14, I14);
        float gii = qround(acc[1][r] + bi, S14, I14);
        float gin = qround(acc[2][r] + bn, S14, I14);
        float ghr = qround(acc[3][r] + cr, S14, I14);
        float ghi = qround(acc[4][r] + ci, S14, I14);
        float ghn = qround(acc[5][r] + cn, S14, I14);
        float resetg = qsigmoid_dev(gir + ghr);
        float inputg = qsigmoid_dev(gii + ghi);
        float hn  = qround(ghn, S27, I27);
        float rh  = qround(resetg * hn, S15, I15);
        float newg = qtanh_dev(rh + gin);
        float nh  = qround(hv, S15, I15);
        out[(size_t)m * Hsz + n] = newg + inputg * (nh - newg);
    }
}

// ---------------- fallback: bf16x3 (used only if ws too small) -------------
__global__ __launch_bounds__(256, 2) void qgru_mfma_bf16x3(
    const float* __restrict__ x, const float* __restrict__ hid,
    const float* __restrict__ wih, const float* __restrict__ whh,
    const float* __restrict__ bih, const float* __restrict__ bhh,
    float* __restrict__ out)
{
    __shared__ __align__(16) unsigned short lds[16384];

    const int t = threadIdx.x, lane = t & 63, wid = t >> 6;
    const int mt = wid >> 1, nt = wid & 1;
    const int m0 = blockIdx.x * BM, n0 = blockIdx.y * BN;
    const int s_r = t >> 2, s_k = (t & 3) << 2;
    const int s_kh = s_k >> 3, s_j = s_k & 7, s_rt = s_r >> 5, s_r32 = s_r & 31;

    const float* gA[2];
    gA[0] = x   + (size_t)(m0 + s_r) * Ksz + s_k;
    gA[1] = hid + (size_t)(m0 + s_r) * Ksz + s_k;
    const float* gW[6];
#pragma unroll
    for (int g = 0; g < 3; ++g) {
        gW[g]     = wih + (size_t)(g * Hsz + n0 + s_r) * Ksz + s_k;
        gW[g + 3] = whh + (size_t)(g * Hsz + n0 + s_r) * Ksz + s_k;
    }
    const int lh = lane >> 5, l32 = lane & 31;

    f32x16 acc[6];
#pragma unroll
    for (int g = 0; g < 6; ++g)
#pragma unroll
        for (int i = 0; i < 16; ++i) acc[g][i] = 0.0f;

    float4 vA[2], vW[6];
#pragma unroll
    for (int tt = 0; tt < 2; ++tt) vA[tt] = *(const float4*)gA[tt];
#pragma unroll
    for (int g = 0; g < 6; ++g)    vW[g]  = *(const float4*)gW[g];

    for (int k0 = 0; k0 < Ksz; k0 += 16) {
        __syncthreads();
#pragma unroll
        for (int tt = 0; tt < 2; ++tt) {
            unsigned h0, h1, l0, l1;
            split2(vA[tt].x, vA[tt].y, h0, l0);
            split2(vA[tt].z, vA[tt].w, h1, l1);
            unsigned bH = ((((tt*2+0)*2+s_rt)*2+s_kh)*32+s_r32)*8 + s_j;
            unsigned bL = ((((tt*2+1)*2+s_rt)*2+s_kh)*32+s_r32)*8 + s_j;
            *reinterpret_cast<uint2*>(&lds[bH]) = make_uint2(h0, h1);
            *reinterpret_cast<uint2*>(&lds[bL]) = make_uint2(l0, l1);
        }
#pragma unroll
        for (int g = 0; g < 6; ++g) {
            unsigned h0, h1, l0, l1;
            split2(vW[g].x, vW[g].y, h0, l0);
            split2(vW[g].z, vW[g].w, h1, l1);
            unsigned bH = 4096u + ((((g*2+0)*2+s_rt)*2+s_kh)*32+s_r32)*8 + s_j;
            unsigned bL = 4096u + ((((g*2+1)*2+s_rt)*2+s_kh)*32+s_r32)*8 + s_j;
            *reinterpret_cast<uint2*>(&lds[bH]) = make_uint2(h0, h1);
            *reinterpret_cast<uint2*>(&lds[bL]) = make_uint2(l0, l1);
        }
        __syncthreads();
        const int kn = (k0 + 16 < Ksz) ? (k0 + 16) : 0;
#pragma unroll
        for (int tt = 0; tt < 2; ++tt) vA[tt] = *(const float4*)(gA[tt] + kn);
#pragma unroll
        for (int g = 0; g < 6; ++g)    vW[g]  = *(const float4*)(gW[g] + kn);

        const bf16x8 ax_hi = *reinterpret_cast<const bf16x8*>(&lds[((((0)*2+mt)*2+lh)*32+l32)*8]);
        const bf16x8 ax_lo = *reinterpret_cast<const bf16x8*>(&lds[((((1)*2+mt)*2+lh)*32+l32)*8]);
        const bf16x8 ah_hi = *reinterpret_cast<const bf16x8*>(&lds[((((2)*2+mt)*2+lh)*32+l32)*8]);
        const bf16x8 ah_lo = *reinterpret_cast<const bf16x8*>(&lds[((((3)*2+mt)*2+lh)*32+l32)*8]);
#pragma unroll
        for (int g = 0; g < 6; ++g) {
            const bf16x8 b_hi = *reinterpret_cast<const bf16x8*>(&lds[4096u + ((((g*2+0)*2+nt)*2+lh)*32+l32)*8]);
            const bf16x8 b_lo = *reinterpret_cast<const bf16x8*>(&lds[4096u + ((((g*2+1)*2+nt)*2+lh)*32+l32)*8]);
            const bf16x8 a_hi = (g < 3) ? ax_hi : ah_hi;
            const bf16x8 a_lo = (g < 3) ? ax_lo : ah_lo;
            acc[g] = __builtin_amdgcn_mfma_f32_32x32x16_bf16(a_hi, b_hi, acc[g], 0, 0, 0);
            acc[g] = __builtin_amdgcn_mfma_f32_32x32x16_bf16(a_hi, b_lo, acc[g], 0, 0, 0);
            acc[g] = __builtin_amdgcn_mfma_f32_32x32x16_bf16(a_lo, b_hi, acc[g], 0, 0, 0);
        }
    }

    constexpr float S14 = 16384.0f,     I14 = 1.0f / 16384.0f;
    constexpr float S15 = 32768.0f,     I15 = 1.0f / 32768.0f;
    constexpr float S27 = 134217728.0f, I27 = 1.0f / 134217728.0f;
    const int n = n0 + nt * 32 + l32;
    const float br = bih[n], bi = bih[n + 512], bn = bih[n + 1024];
    const float cr = bhh[n], ci = bhh[n + 512], cn = bhh[n + 1024];
#pragma unroll
    for (int r = 0; r < 16; ++r) {
        const int row = (r & 3) + 8 * (r >> 2) + 4 * lh;
        const int m   = m0 + mt * 32 + row;
        const float hv = hid[(size_t)m * Hsz + n];
        float gir = qround(acc[0][r] + br, S14, I14);
        float gii = qround(acc[1][r] + bi, S14, I14);
        float gin = qround(acc[2][r] + bn, S14, I14);
        float ghr = qround(acc[3][r] + cr, S14, I14);
        float ghi = qround(acc[4][r] + ci, S14, I14);
        float ghn = qround(acc[5][r] + cn, S14, I14);
        float resetg = qsigmoid_dev(gir + ghr);
        float inputg = qsigmoid_dev(gii + ghi);
        float hn  = qround(ghn, S27, I27);
        float rh  = qround(resetg * hn, S15, I15);
        float newg = qtanh_dev(rh + gin);
        float nh  = qround(hv, S15, I15);
        out[(size_t)m * Hsz + n] = newg + inputg * (nh - newg);
    }
}

extern "C" void kernel_launch(void* const* d_in, const int* in_sizes, int n_in,
                              void* d_out, int out_size, void* d_ws, size_t ws_size,
                              hipStream_t stream) {
    const float* x   = (const float*)d_in[0];
    const float* hid = (const float*)d_in[1];
    const float* wih = (const float*)d_in[2];
    const float* whh = (const float*)d_in[3];
    const float* bih = (const float*)d_in[4];
    const float* bhh = (const float*)d_in[5];
    float* out = (float*)d_out;
    dim3 grid(Bsz / BM, Hsz / BN);   // x-major: consecutive blocks share W chunks

    if (ws_size >= WS_NEED) {
        wcvt_f16<<<96, 256, 0, stream>>>(wih, whh, (_Float16*)d_ws);
        qgru_hyb<<<grid, dim3(256), 0, stream>>>(
            x, hid, (const _Float16*)d_ws, bih, bhh, out);
    } else {
        qgru_mfma_bf16x3<<<grid, dim3(256), 0, stream>>>(
            x, hid, wih, whh, bih, bhh, out);
    }
}

// Round 10
// 138.499 us; speedup vs baseline: 1.2878x; 1.0089x over previous
//
#include <hip/hip_runtime.h>
#include <math.h>

// QGRUCell — Round 10: hybrid staging, coalescing + bank fixes vs R9.
//   A (x,h): idx->(arr,row,li) mapping gives 8 full 128B lines per wave-load
//            (one float4/lane); ds_write_b64 with rotation swizzle
//            rsw=(row + li>>1)&31 -> uniform bank spread (was 8-way conflict).
//   W: unchanged pre-tiled ws + contiguous 1KB global_load_lds (R5 path).
// KT=32, slab 32KB (A 8 + W 24), dbuf 64KB, 16 barriers.

typedef _Float16 f16x8  __attribute__((ext_vector_type(8)));
typedef _Float16 f16x4  __attribute__((ext_vector_type(4)));
typedef __bf16   bf16x8 __attribute__((ext_vector_type(8)));
typedef float    f32x16 __attribute__((ext_vector_type(16)));

namespace {

constexpr int Bsz = 8192, Ksz = 512, Hsz = 512;
constexpr int BM = 64, BN = 64;

// ws (f16): W only. chunk(g, N32, K16) = (g*16+N32)*32 + K16, 512 f16 each,
// chunk pos(row,k) = (k>>3)*256 + row*8 + (k&7). 3072 chunks = 3 MB.
constexpr unsigned NCHW    = 3072u;
constexpr size_t   WS_NEED = (size_t)NCHW * 512u * 2u;   // 3,145,728 B

__device__ __forceinline__ float qround(float x, float s, float invs) {
    return floorf(x * s + 0.5f) * invs;
}

__device__ __forceinline__ float qsigmoid_dev(float x) {
    float iq = floorf(x * 134217728.0f + 0.5f);
    iq = fminf(fmaxf(iq, -2147483648.0f), 2147483648.0f);
    float e = __expf(-iq * 7.450580596923828125e-9f);
    float s = __builtin_amdgcn_rcpf(1.0f + e);
    float q31 = floorf(s * 2147483648.0f + 0.5f);
    float q15 = floorf(q31 * 1.52587890625e-5f + 0.5f);
    return q15 * 3.0517578125e-5f;
}

__device__ __forceinline__ float qtanh_dev(float x) {
    float iq = floorf(x * 134217728.0f + 0.5f);
    iq = fminf(fmaxf(iq, -2147483648.0f), 2147483648.0f);
    float z = iq * 7.450580596923828125e-9f;
    float e = __expf(2.0f * z);
    float t = 1.0f - 2.0f * __builtin_amdgcn_rcpf(e + 1.0f);
    float q31 = floorf(t * 2147483648.0f + 0.5f);
    float q15 = floorf(q31 * 1.52587890625e-5f + 0.5f);
    return q15 * 3.0517578125e-5f;
}

__device__ __forceinline__ void dma16(const void* g, void* l) {
    __builtin_amdgcn_global_load_lds(
        (const __attribute__((address_space(1))) unsigned int*)g,
        (__attribute__((address_space(3))) unsigned int*)l, 16, 0, 0);
}

__device__ __forceinline__ f16x4 cvt4(float4 a) {   // RNE casts
    f16x4 r;
    r[0] = (_Float16)a.x; r[1] = (_Float16)a.y;
    r[2] = (_Float16)a.z; r[3] = (_Float16)a.w;
    return r;
}

__device__ __forceinline__ void split2(float a, float b, unsigned& hi, unsigned& lo) {
    unsigned ua = __float_as_uint(a); ua += 0x7fffu + ((ua >> 16) & 1u);
    unsigned ub = __float_as_uint(b); ub += 0x7fffu + ((ub >> 16) & 1u);
    hi = (ua >> 16) | (ub & 0xffff0000u);
    float ra = a - __uint_as_float(ua & 0xffff0000u);
    float rb = b - __uint_as_float(ub & 0xffff0000u);
    unsigned va = __float_as_uint(ra); va += 0x7fffu + ((va >> 16) & 1u);
    unsigned vb = __float_as_uint(rb); vb += 0x7fffu + ((vb >> 16) & 1u);
    lo = (va >> 16) | (vb & 0xffff0000u);
}

} // namespace

// ---------------- pre-pass: weights fp32 -> f16 frag-order chunks ----------
__global__ __launch_bounds__(256) void wcvt_f16(
    const float* __restrict__ wih, const float* __restrict__ whh,
    _Float16* __restrict__ ws)
{
    __shared__ __align__(16) _Float16 lt[16384];

    const int b   = blockIdx.x;            // 0..95
    const int tid = threadIdx.x;
    const int g   = b >> 4, N32 = b & 15;
    const int rowLocal = (g % 3) * 512 + N32 * 32;
    const float* src = (g < 3 ? wih : whh) + (size_t)rowLocal * 512u;
    const unsigned chbase = (unsigned)((g * 16 + N32) * 32);

#pragma unroll
    for (int rep = 0; rep < 16; ++rep) {
        const int idx = rep * 256 + tid;
        const int row = idx >> 7;
        const int q   = idx & 127;
        const float4 v = *(const float4*)(src + (size_t)row * 512 + q * 4);
        const int K16  = q >> 2;
        const int kh   = (q >> 1) & 1;
        const int half = (q & 1) * 4;
        const int rsw  = (row + (q >> 1)) & 31;
        *(f16x4*)&lt[K16 * 512 + kh * 256 + rsw * 8 + half] = cvt4(v);
    }
    __syncthreads();

    const int wid = tid >> 6, lane = tid & 63;
    const int kh  = lane >> 5, row = lane & 31;
#pragma unroll
    for (int cc = 0; cc < 8; ++cc) {
        const int K16 = wid * 8 + cc;
        const int rsw = (row + 2 * K16 + kh) & 31;
        const f16x8 o = *(const f16x8*)&lt[K16 * 512 + kh * 256 + rsw * 8];
        *(f16x8*)(ws + (size_t)(chbase + K16) * 512u + lane * 8) = o;
    }
}

// ---------------- main: hybrid-staged GEMM + quantized GRU epilogue --------
// Slab (16384 f16 = 32KB):
//   A chunk ((arr*2+mtc)*2+ks2)*512, pos = kh*256 + rsw*8 + (k&7),
//     rsw = (row32 + 2*ks2 + kh) & 31  (rotation vs bank conflicts) [0,4096)
//   W chunk 4096 + ((g*2+ntc)*2+ks2)*512, pos = kh*256 + row*8 + (k&7)
__global__ __launch_bounds__(256, 2) void qgru_hyb2(
    const float* __restrict__ x, const float* __restrict__ hid,
    const _Float16* __restrict__ ws,
    const float* __restrict__ bih, const float* __restrict__ bhh,
    float* __restrict__ out)
{
    __shared__ __align__(16) _Float16 lds[32768];   // 64 KB (2 x 32KB slabs)

    const int t = threadIdx.x, lane = t & 63, wid = t >> 6;
    const int mt = wid >> 1, nt = wid & 1;
    const int m0 = blockIdx.x * BM, n0 = blockIdx.y * BN;

    // ---- W DMA table: 24 chunks/step, 6 per wave, 1KB contiguous each ----
    unsigned goff[6];
    int      ldst[6];
#pragma unroll
    for (int c = 0; c < 6; ++c) {
        const int q = wid * 6 + c;              // 0..23
        const int g = q >> 2, ntc = (q >> 1) & 1, ks2 = q & 1;
        const unsigned ch = (unsigned)((g * 16 + (n0 >> 5) + ntc) * 32) + (unsigned)ks2;
        goff[c] = ch * 1024u + (unsigned)lane * 16u;
        ldst[c] = 4096 + ((g * 2 + ntc) * 2 + ks2) * 512;
    }

    // ---- A staging: 4 reps x 256 threads = 2 arr x 64 rows x 8 k-quads.
    //      One float4/lane; 64 consecutive idx = 8 rows x full 128B line. ----
    const float* asrc_[4];
    int adst_[4];
#pragma unroll
    for (int r = 0; r < 4; ++r) {
        const int idx = r * 256 + t;
        const int arr = idx >> 9, row = (idx >> 3) & 63, li = idx & 7;
        const int K16 = li >> 2, kh = (li >> 1) & 1, half = li & 1;
        const int rsw = ((row & 31) + (li >> 1)) & 31;
        asrc_[r] = (arr ? hid : x) + (size_t)(m0 + row) * Ksz + li * 4;
        adst_[r] = ((arr * 2 + (row >> 5)) * 2 + K16) * 512
                 + kh * 256 + rsw * 8 + half * 4;
    }

    f32x16 acc[6];
#pragma unroll
    for (int g = 0; g < 6; ++g)
#pragma unroll
        for (int i = 0; i < 16; ++i) acc[g][i] = 0.0f;

    const char* wsb = (const char*)ws;
    const int l32 = lane & 31, kh = lane >> 5;
    const int lfoW = kh * 256 + l32 * 8;

    // ---- prologue: stage step 0 into slab 0 ----
#pragma unroll
    for (int c = 0; c < 6; ++c)
        dma16(wsb + goff[c], &lds[ldst[c]]);
#pragma unroll
    for (int r = 0; r < 4; ++r)
        *(f16x4*)&lds[adst_[r]] = cvt4(*(const float4*)asrc_[r]);

    for (int step = 0; step < 16; ++step) {
        __syncthreads();   // slab's DMA + ds_writes drained; prev reads done

        // prefetch step+1: W-DMA + A global loads (issued early for latency)
        float4 p[4];
        const bool pf = (step + 1 < 16);
        if (pf) {
            const unsigned kb = (unsigned)(step + 1) * 2048u;
            const int nb = ((step + 1) & 1) * 16384;
#pragma unroll
            for (int c = 0; c < 6; ++c)
                dma16(wsb + goff[c] + kb, &lds[nb + ldst[c]]);
#pragma unroll
            for (int r = 0; r < 4; ++r)
                p[r] = *(const float4*)(asrc_[r] + (step + 1) * 32);
        }

        // compute current slab
        const int cb = (step & 1) * 16384;
#pragma unroll
        for (int ks2 = 0; ks2 < 2; ++ks2) {
            const int rswA = (l32 + 2 * ks2 + kh) & 31;
            const int lfA  = cb + kh * 256 + rswA * 8;
            const f16x8 ax = *(const f16x8*)&lds[lfA + ((0 + mt) * 2 + ks2) * 512];
            const f16x8 ah = *(const f16x8*)&lds[lfA + ((2 + mt) * 2 + ks2) * 512];
#pragma unroll
            for (int g = 0; g < 6; ++g) {
                const f16x8 b = *(const f16x8*)&lds[cb + 4096
                                  + ((g * 2 + nt) * 2 + ks2) * 512 + lfoW];
                acc[g] = __builtin_amdgcn_mfma_f32_32x32x16_f16(
                             g < 3 ? ax : ah, b, acc[g], 0, 0, 0);
            }
        }

        // A ds_writes after compute (keeps lgkm queue clear of frag reads)
        if (pf) {
            const int nb = ((step + 1) & 1) * 16384;
#pragma unroll
            for (int r = 0; r < 4; ++r)
                *(f16x4*)&lds[nb + adst_[r]] = cvt4(p[r]);
        }
    }

    // ---- epilogue: quantized GRU gate chain ----
    constexpr float S14 = 16384.0f,     I14 = 1.0f / 16384.0f;
    constexpr float S15 = 32768.0f,     I15 = 1.0f / 32768.0f;
    constexpr float S27 = 134217728.0f, I27 = 1.0f / 134217728.0f;

    const int n = n0 + nt * 32 + l32;
    const float br = bih[n], bi = bih[n + 512], bn = bih[n + 1024];
    const float cr = bhh[n], ci = bhh[n + 512], cn = bhh[n + 1024];

#pragma unroll
    for (int r = 0; r < 16; ++r) {
        const int row = (r & 3) + 8 * (r >> 2) + 4 * kh;
        const int m   = m0 + mt * 32 + row;
        const float hv = hid[(size_t)m * Hsz + n];

        float gir = qround(acc[0][r] + br, S14, I14);
        float gii = qround(acc[1][r] + bi, S14, I14);
        float gin = qround(acc[2][r] + bn, S14, I14);
        float ghr = qround(acc[3][r] + cr, S14, I14);
        float ghi = qround(acc[4][r] + ci, S14, I14);
        float ghn = qround(acc[5][r] + cn, S14, I14);
        float resetg = qsigmoid_dev(gir + ghr);
        float inputg = qsigmoid_dev(gii + ghi);
        float hn  = qround(ghn, S27, I27);
        float rh  = qround(resetg * hn, S15, I15);
        float newg = qtanh_dev(rh + gin);
        float nh  = qround(hv, S15, I15);
        out[(size_t)m * Hsz + n] = newg + inputg * (nh - newg);
    }
}

// ---------------- fallback: bf16x3 (used only if ws too small) -------------
__global__ __launch_bounds__(256, 2) void qgru_mfma_bf16x3(
    const float* __restrict__ x, const float* __restrict__ hid,
    const float* __restrict__ wih, const float* __restrict__ whh,
    const float* __restrict__ bih, const float* __restrict__ bhh,
    float* __restrict__ out)
{
    __shared__ __align__(16) unsigned short lds[16384];

    const int t = threadIdx.x, lane = t & 63, wid = t >> 6;
    const int mt = wid >> 1, nt = wid & 1;
    const int m0 = blockIdx.x * BM, n0 = blockIdx.y * BN;
    const int s_r = t >> 2, s_k = (t & 3) << 2;
    const int s_kh = s_k >> 3, s_j = s_k & 7, s_rt = s_r >> 5, s_r32 = s_r & 31;

    const float* gA[2];
    gA[0] = x   + (size_t)(m0 + s_r) * Ksz + s_k;
    gA[1] = hid + (size_t)(m0 + s_r) * Ksz + s_k;
    const float* gW[6];
#pragma unroll
    for (int g = 0; g < 3; ++g) {
        gW[g]     = wih + (size_t)(g * Hsz + n0 + s_r) * Ksz + s_k;
        gW[g + 3] = whh + (size_t)(g * Hsz + n0 + s_r) * Ksz + s_k;
    }
    const int lh = lane >> 5, l32 = lane & 31;

    f32x16 acc[6];
#pragma unroll
    for (int g = 0; g < 6; ++g)
#pragma unroll
        for (int i = 0; i < 16; ++i) acc[g][i] = 0.0f;

    float4 vA[2], vW[6];
#pragma unroll
    for (int tt = 0; tt < 2; ++tt) vA[tt] = *(const float4*)gA[tt];
#pragma unroll
    for (int g = 0; g < 6; ++g)    vW[g]  = *(const float4*)gW[g];

    for (int k0 = 0; k0 < Ksz; k0 += 16) {
        __syncthreads();
#pragma unroll
        for (int tt = 0; tt < 2; ++tt) {
            unsigned h0, h1, l0, l1;
            split2(vA[tt].x, vA[tt].y, h0, l0);
            split2(vA[tt].z, vA[tt].w, h1, l1);
            unsigned bH = ((((tt*2+0)*2+s_rt)*2+s_kh)*32+s_r32)*8 + s_j;
            unsigned bL = ((((tt*2+1)*2+s_rt)*2+s_kh)*32+s_r32)*8 + s_j;
            *reinterpret_cast<uint2*>(&lds[bH]) = make_uint2(h0, h1);
            *reinterpret_cast<uint2*>(&lds[bL]) = make_uint2(l0, l1);
        }
#pragma unroll
        for (int g = 0; g < 6; ++g) {
            unsigned h0, h1, l0, l1;
            split2(vW[g].x, vW[g].y, h0, l0);
            split2(vW[g].z, vW[g].w, h1, l1);
            unsigned bH = 4096u + ((((g*2+0)*2+s_rt)*2+s_kh)*32+s_r32)*8 + s_j;
            unsigned bL = 4096u + ((((g*2+1)*2+s_rt)*2+s_kh)*32+s_r32)*8 + s_j;
            *reinterpret_cast<uint2*>(&lds[bH]) = make_uint2(h0, h1);
            *reinterpret_cast<uint2*>(&lds[bL]) = make_uint2(l0, l1);
        }
        __syncthreads();
        const int kn = (k0 + 16 < Ksz) ? (k0 + 16) : 0;
#pragma unroll
        for (int tt = 0; tt < 2; ++tt) vA[tt] = *(const float4*)(gA[tt] + kn);
#pragma unroll
        for (int g = 0; g < 6; ++g)    vW[g]  = *(const float4*)(gW[g] + kn);

        const bf16x8 ax_hi = *reinterpret_cast<const bf16x8*>(&lds[((((0)*2+mt)*2+lh)*32+l32)*8]);
        const bf16x8 ax_lo = *reinterpret_cast<const bf16x8*>(&lds[((((1)*2+mt)*2+lh)*32+l32)*8]);
        const bf16x8 ah_hi = *reinterpret_cast<const bf16x8*>(&lds[((((2)*2+mt)*2+lh)*32+l32)*8]);
        const bf16x8 ah_lo = *reinterpret_cast<const bf16x8*>(&lds[((((3)*2+mt)*2+lh)*32+l32)*8]);
#pragma unroll
        for (int g = 0; g < 6; ++g) {
            const bf16x8 b_hi = *reinterpret_cast<const bf16x8*>(&lds[4096u + ((((g*2+0)*2+nt)*2+lh)*32+l32)*8]);
            const bf16x8 b_lo = *reinterpret_cast<const bf16x8*>(&lds[4096u + ((((g*2+1)*2+nt)*2+lh)*32+l32)*8]);
            const bf16x8 a_hi = (g < 3) ? ax_hi : ah_hi;
            const bf16x8 a_lo = (g < 3) ? ax_lo : ah_lo;
            acc[g] = __builtin_amdgcn_mfma_f32_32x32x16_bf16(a_hi, b_hi, acc[g], 0, 0, 0);
            acc[g] = __builtin_amdgcn_mfma_f32_32x32x16_bf16(a_hi, b_lo, acc[g], 0, 0, 0);
            acc[g] = __builtin_amdgcn_mfma_f32_32x32x16_bf16(a_lo, b_hi, acc[g], 0, 0, 0);
        }
    }

    constexpr float S14 = 16384.0f,     I14 = 1.0f / 16384.0f;
    constexpr float S15 = 32768.0f,     I15 = 1.0f / 32768.0f;
    constexpr float S27 = 134217728.0f, I27 = 1.0f / 134217728.0f;
    const int n = n0 + nt * 32 + l32;
    const float br = bih[n], bi = bih[n + 512], bn = bih[n + 1024];
    const float cr = bhh[n], ci = bhh[n + 512], cn = bhh[n + 1024];
#pragma unroll
    for (int r = 0; r < 16; ++r) {
        const int row = (r & 3) + 8 * (r >> 2) + 4 * lh;
        const int m   = m0 + mt * 32 + row;
        const float hv = hid[(size_t)m * Hsz + n];
        float gir = qround(acc[0][r] + br, S14, I14);
        float gii = qround(acc[1][r] + bi, S14, I14);
        float gin = qround(acc[2][r] + bn, S14, I14);
        float ghr = qround(acc[3][r] + cr, S14, I14);
        float ghi = qround(acc[4][r] + ci, S14, I14);
        float ghn = qround(acc[5][r] + cn, S14, I14);
        float resetg = qsigmoid_dev(gir + ghr);
        float inputg = qsigmoid_dev(gii + ghi);
        float hn  = qround(ghn, S27, I27);
        float rh  = qround(resetg * hn, S15, I15);
        float newg = qtanh_dev(rh + gin);
        float nh  = qround(hv, S15, I15);
        out[(size_t)m * Hsz + n] = newg + inputg * (nh - newg);
    }
}

extern "C" void kernel_launch(void* const* d_in, const int* in_sizes, int n_in,
                              void* d_out, int out_size, void* d_ws, size_t ws_size,
                              hipStream_t stream) {
    const float* x   = (const float*)d_in[0];
    const float* hid = (const float*)d_in[1];
    const float* wih = (const float*)d_in[2];
    const float* whh = (const float*)d_in[3];
    const float* bih = (const float*)d_in[4];
    const float* bhh = (const float*)d_in[5];
    float* out = (float*)d_out;
    dim3 grid(Bsz / BM, Hsz / BN);   // x-major: consecutive blocks share W chunks

    if (ws_size >= WS_NEED) {
        wcvt_f16<<<96, 256, 0, stream>>>(wih, whh, (_Float16*)d_ws);
        qgru_hyb2<<<grid, dim3(256), 0, stream>>>(
            x, hid, (const _Float16*)d_ws, bih, bhh, out);
    } else {
        qgru_mfma_bf16x3<<<grid, dim3(256), 0, stream>>>(
            x, hid, wih, whh, bih, bhh, out);
    }
}